// Round 1
// baseline (198.587 us; speedup 1.0000x reference)
//
#include <hip/hip_runtime.h>

// Volume rendering (NeRF-style fancy_integration), f32 in/out.
// B=4, R=32768, S=64  -> 131072 rays, 64 samples each.
// One 64-lane wave per ray; lane i handles sample i.

#define NSAMP 64
#define EPS_W 1e-10f
#define DELTA_INF_V 1e10f

__global__ __launch_bounds__(256) void volrend_kernel(
    const float* __restrict__ rgb,      // [n_rays, 64, 3]
    const float* __restrict__ sigma,    // [n_rays, 64]
    const float* __restrict__ z_vals,   // [n_rays, 64]
    float* __restrict__ rgb_out,        // [n_rays, 3]
    float* __restrict__ depth_out,      // [n_rays]
    float* __restrict__ weights_out,    // [n_rays, 64]
    int n_rays)
{
    const int lane = threadIdx.x & 63;
    const int wave = threadIdx.x >> 6;
    const int ray  = blockIdx.x * (blockDim.x >> 6) + wave;
    if (ray >= n_rays) return;

    const long long base = (long long)ray * NSAMP + lane;

    // Coalesced per-lane loads
    const float sg = sigma[base];
    const float z  = z_vals[base];
    const float* rp = rgb + base * 3;
    const float cr = rp[0];
    const float cg = rp[1];
    const float cb = rp[2];

    // delta_i = z_{i+1} - z_i ; last = 1e10
    const float z_next = __shfl_down(z, 1);
    const float delta  = (lane == NSAMP - 1) ? DELTA_INF_V : (z_next - z);

    // alpha = 1 - exp(-delta * relu(sigma))
    const float alpha = 1.0f - __expf(-delta * fmaxf(sg, 0.0f));

    // exclusive prefix product of (1 - alpha + eps) across the wave
    float p = 1.0f - alpha + EPS_W;
    #pragma unroll
    for (int off = 1; off < 64; off <<= 1) {
        const float o = __shfl_up(p, off);
        if (lane >= off) p *= o;
    }
    float T = __shfl_up(p, 1);
    if (lane == 0) T = 1.0f;

    const float w = alpha * T;

    // weights output (coalesced)
    weights_out[base] = w;

    // butterfly reductions: rgb (3) + depth (1)
    float sr = w * cr;
    float sg2 = w * cg;
    float sb = w * cb;
    float sd = w * z;
    #pragma unroll
    for (int off = 32; off > 0; off >>= 1) {
        sr  += __shfl_down(sr, off);
        sg2 += __shfl_down(sg2, off);
        sb  += __shfl_down(sb, off);
        sd  += __shfl_down(sd, off);
    }
    if (lane == 0) {
        rgb_out[(long long)ray * 3 + 0] = sr;
        rgb_out[(long long)ray * 3 + 1] = sg2;
        rgb_out[(long long)ray * 3 + 2] = sb;
        depth_out[ray] = sd;
    }
}

extern "C" void kernel_launch(void* const* d_in, const int* in_sizes, int n_in,
                              void* d_out, int out_size, void* d_ws, size_t ws_size,
                              hipStream_t stream) {
    const float* rgb    = (const float*)d_in[0];   // [B,R,S,3]
    const float* sigma  = (const float*)d_in[1];   // [B,R,S,1]
    const float* z_vals = (const float*)d_in[2];   // [B,R,S,1]

    const int n_rays = in_sizes[1] / NSAMP;        // B*R = 131072

    float* out        = (float*)d_out;
    float* rgb_out    = out;                              // n_rays*3
    float* depth_out  = out + (long long)n_rays * 3;      // n_rays
    float* weights_out= out + (long long)n_rays * 4;      // n_rays*64

    const int block = 256;                 // 4 waves = 4 rays per block
    const int rays_per_block = block / 64;
    const int grid = (n_rays + rays_per_block - 1) / rays_per_block;

    volrend_kernel<<<grid, block, 0, stream>>>(
        rgb, sigma, z_vals, rgb_out, depth_out, weights_out, n_rays);
}